// Round 8
// baseline (1922.512 us; speedup 1.0000x reference)
//
#include <hip/hip_runtime.h>
#include <hip/hip_bf16.h>
#include <stdint.h>

#define D 64
typedef __hip_bfloat16 bf16;
typedef unsigned short u16;

__device__ __forceinline__ float bf2f(u16 u) { return __uint_as_float(((uint32_t)u) << 16); }
__device__ __forceinline__ float lo16(uint32_t w) { return __uint_as_float(w << 16); }
__device__ __forceinline__ float hi16(uint32_t w) { return __uint_as_float(w & 0xffff0000u); }

template <bool F32>
__device__ __forceinline__ float ld(const void* p, int i) {
    if constexpr (F32) return ((const float*)p)[i];
    else return bf2f(((const u16*)p)[i]);
}

// ---- dtype oracle ----
__global__ __launch_bounds__(256) void detect_kernel(const void* x, const int* ei, int* flags) {
    __shared__ float smax[256];
    __shared__ int sor[256];
    int t = threadIdx.x;
    const u16* xs = (const u16*)x;
    float mx = 0.f;
#pragma unroll
    for (int i = 0; i < 16; ++i) {
        float a = fabsf(bf2f(xs[t * 16 + i]));
        if (!(a == a)) a = 1e30f;
        mx = fmaxf(mx, a);
    }
    int any = 0;
#pragma unroll
    for (int i = 0; i < 8; ++i) any |= ei[2 * (t * 8 + i) + 1];
    smax[t] = mx;
    sor[t] = any;
    __syncthreads();
    for (int s = 128; s > 0; s >>= 1) {
        if (t < s) { smax[t] = fmaxf(smax[t], smax[t + s]); sor[t] |= sor[t + s]; }
        __syncthreads();
    }
    if (t == 0) {
        flags[0] = (smax[0] > 1000.f) ? 1 : 0;
        flags[1] = (sor[0] != 0) ? 1 : 0;
    }
}

// ---- node_transform (proven) ----
template <bool F32>
__device__ __forceinline__ void nt_body(const void* x, const void* Wnt, const void* bnt,
                                        float* h, int N) {
    int gid = blockIdx.x * 256 + threadIdx.x;
    if (gid >= N * D) return;
    int n = gid >> 6, c = gid & 63;
    float acc = ld<F32>(bnt, c);
#pragma unroll
    for (int k = 0; k < 6; ++k)
        acc = fmaf(ld<F32>(x, n * 6 + k), ld<F32>(Wnt, c * 6 + k), acc);
    h[gid] = fmaxf(acc, 0.f);
}
__global__ __launch_bounds__(256) void nt_kernel(const int* flags, const void* x, const void* Wnt,
                                                 const void* bnt, float* h, int N) {
    if (flags[0]) nt_body<true>(x, Wnt, bnt, h, N);
    else          nt_body<false>(x, Wnt, bnt, h, N);
}

// ---- m = h @ weight[layer] (proven) ----
template <bool F32>
__device__ __forceinline__ void m_body(const float* h, const void* W, int woff, float* m, int N) {
    int lane = threadIdx.x & 63;
    int n = blockIdx.x * 4 + (threadIdx.x >> 6);
    if (n >= N) return;
    const float* hrow = h + (size_t)n * D;
    float acc = 0.f;
#pragma unroll
    for (int k = 0; k < D; ++k)
        acc = fmaf(hrow[k], ld<F32>(W, woff + k * D + lane), acc);
    m[(size_t)n * D + lane] = acc;
}
__global__ __launch_bounds__(256) void m_kernel(const int* flags, const float* h, const void* W,
                                                int woff, float* m, int N) {
    if (flags[0]) m_body<true>(h, W, woff, m, N);
    else          m_body<false>(h, W, woff, m, N);
}

// ---- scatter (round-1 verbatim, proven) ----
__global__ __launch_bounds__(256) void scatter_kernel(const int* flags, const float* __restrict__ m,
                                                      const int* __restrict__ ei,
                                                      float* __restrict__ agg, int E, int N) {
    int e = blockIdx.x * 4 + (threadIdx.x >> 6);
    if (e >= E) return;
    int lane = threadIdx.x & 63;
    int src, dst;
    if (flags[1]) { src = ei[e];     dst = ei[E + e]; }
    else          { src = ei[2 * e]; dst = ei[2 * (E + e)]; }
    if ((unsigned)src >= (unsigned)N || (unsigned)dst >= (unsigned)N) return;
    float v = m[(size_t)src * D + lane];
    atomicAdd(&agg[(size_t)dst * D + lane], v);
}

// ---- weight dword-transpose (bf16 mode): WT2[mat][kk*192 + r] = src32[mat][r*32 + kk]
//      src32 row r holds 32 dwords = 64 bf16 (pairs k=2kk,2kk+1). Pure 192x32 dword transpose.
__global__ __launch_bounds__(256) void wtrans_kernel(const uint32_t* __restrict__ Wih,
                                                     const uint32_t* __restrict__ Whh,
                                                     uint32_t* __restrict__ WT2) {
    int i = blockIdx.x * 256 + threadIdx.x;
    if (i >= 12288) return;
    int mat = i / 6144, rem = i % 6144;
    int kk = rem / 192, r = rem % 192;
    const uint32_t* src = mat ? Whh : Wih;
    WT2[i] = src[r * 32 + kk];
}

// ---- GRU fast path: lane = channel. Block = 256 threads = 16 nodes (4/wave).
//      agg/h rows staged in LDS (broadcast reads); weights from transposed copy
//      (coalesced dword loads, L1/L2-hot 48 KB); coalesced output stores.
__device__ __forceinline__ void gru_fast_bf16(float* LA, float* LH, float* LB,
                                              const float* agg, const float* h,
                                              const uint32_t* WT2,
                                              const void* bih, const void* bhh,
                                              float* hout, bf16* obf, int N) {
    int t = threadIdx.x;
    int n0 = blockIdx.x * 16;
    {   // stage 16 agg rows + 16 h rows (coalesced float4), biases
        int row = t >> 4, col = (t & 15) * 4;
        bool v = (n0 + row) < N;
        const float4 va = v ? *(const float4*)(agg + (size_t)(n0 + row) * D + col)
                            : make_float4(0.f, 0.f, 0.f, 0.f);
        const float4 vh = v ? *(const float4*)(h + (size_t)(n0 + row) * D + col)
                            : make_float4(0.f, 0.f, 0.f, 0.f);
        LA[row * 66 + col + 0] = va.x; LA[row * 66 + col + 1] = va.y;
        LA[row * 66 + col + 2] = va.z; LA[row * 66 + col + 3] = va.w;
        LH[row * 66 + col + 0] = vh.x; LH[row * 66 + col + 1] = vh.y;
        LH[row * 66 + col + 2] = vh.z; LH[row * 66 + col + 3] = vh.w;
        if (t < 192) {
            LB[t] = bf2f(((const u16*)bih)[t]);
            LB[192 + t] = bf2f(((const u16*)bhh)[t]);
        }
    }
    __syncthreads();
    int lane = t & 63;
    int w4 = (t >> 6) * 4;  // this wave's first node slot (0,4,8,12)
    const uint32_t* WT = WT2;          // Wih^T  (gate rows r = g*64+c)
    const uint32_t* VT = WT2 + 6144;   // Whh^T
    float br = LB[lane] + LB[192 + lane];
    float bz = LB[64 + lane] + LB[256 + lane];
    float bi = LB[128 + lane];
    float bh = LB[320 + lane];
    float ra[4], za[4], ia[4], ha[4];
#pragma unroll
    for (int nn = 0; nn < 4; ++nn) { ra[nn] = br; za[nn] = bz; ia[nn] = bi; ha[nn] = bh; }
#pragma unroll 2
    for (int kk = 0; kk < 32; ++kk) {
        uint32_t w0 = WT[kk * 192 + lane];
        uint32_t w1 = WT[kk * 192 + 64 + lane];
        uint32_t w2 = WT[kk * 192 + 128 + lane];
        uint32_t v0 = VT[kk * 192 + lane];
        uint32_t v1 = VT[kk * 192 + 64 + lane];
        uint32_t v2 = VT[kk * 192 + 128 + lane];
        float w0l = lo16(w0), w0h = hi16(w0), w1l = lo16(w1), w1h = hi16(w1);
        float w2l = lo16(w2), w2h = hi16(w2), v0l = lo16(v0), v0h = hi16(v0);
        float v1l = lo16(v1), v1h = hi16(v1), v2l = lo16(v2), v2h = hi16(v2);
#pragma unroll
        for (int nn = 0; nn < 4; ++nn) {
            int rr = w4 + nn;
            float2 a = *(const float2*)&LA[rr * 66 + 2 * kk];
            float2 hh = *(const float2*)&LH[rr * 66 + 2 * kk];
            ra[nn] = fmaf(a.x, w0l, fmaf(a.y, w0h, ra[nn]));
            za[nn] = fmaf(a.x, w1l, fmaf(a.y, w1h, za[nn]));
            ia[nn] = fmaf(a.x, w2l, fmaf(a.y, w2h, ia[nn]));
            ra[nn] = fmaf(hh.x, v0l, fmaf(hh.y, v0h, ra[nn]));
            za[nn] = fmaf(hh.x, v1l, fmaf(hh.y, v1h, za[nn]));
            ha[nn] = fmaf(hh.x, v2l, fmaf(hh.y, v2h, ha[nn]));
        }
    }
#pragma unroll
    for (int nn = 0; nn < 4; ++nn) {
        int n = n0 + w4 + nn;
        float r = 1.f / (1.f + __expf(-ra[nn]));
        float z = 1.f / (1.f + __expf(-za[nn]));
        float nx = ia[nn] + r * ha[nn];
        float tnh = 1.f - 2.f / (1.f + __expf(2.f * nx));  // tanh, overflow-safe
        float hn = (1.f - z) * tnh + z * LH[(w4 + nn) * 66 + lane];
        if (n < N) {
            if (obf) obf[(size_t)n * D + lane] = __float2bfloat16(hn);
            else     hout[(size_t)n * D + lane] = hn;
        }
    }
}

// F32 body (round-6 verbatim, correctness fallback for fp32 mode)
__device__ __forceinline__ void gru_body_f32(const float* agg, const float* h,
                                             const void* Wih, const void* Whh,
                                             const void* bih, const void* bhh,
                                             float* hout, void* obuf, int N) {
    int lane = threadIdx.x & 63;
    int sub = threadIdx.x >> 6;
    int n = blockIdx.x * 64 + lane;
    if (n >= N) return;
    float ar[D], hv[D];
    const float4* a4 = (const float4*)(agg + (size_t)n * D);
    const float4* h4 = (const float4*)(h + (size_t)n * D);
#pragma unroll
    for (int i = 0; i < 16; ++i) {
        float4 v = a4[i];
        ar[4 * i] = v.x; ar[4 * i + 1] = v.y; ar[4 * i + 2] = v.z; ar[4 * i + 3] = v.w;
        float4 w = h4[i];
        hv[4 * i] = w.x; hv[4 * i + 1] = w.y; hv[4 * i + 2] = w.z; hv[4 * i + 3] = w.w;
    }
    int c0 = sub * 16;
#pragma unroll 1
    for (int cc = 0; cc < 16; ++cc) {
        int c = c0 + cc;
        float air = ld<true>(bih, c), aiz = ld<true>(bih, 64 + c), ain = ld<true>(bih, 128 + c);
        float ahr = ld<true>(bhh, c), ahz = ld<true>(bhh, 64 + c), ahn = ld<true>(bhh, 128 + c);
#pragma unroll
        for (int k = 0; k < D; ++k) {
            air = fmaf(ar[k], ld<true>(Wih, c * D + k), air);
            aiz = fmaf(ar[k], ld<true>(Wih, (64 + c) * D + k), aiz);
            ain = fmaf(ar[k], ld<true>(Wih, (128 + c) * D + k), ain);
            ahr = fmaf(hv[k], ld<true>(Whh, c * D + k), ahr);
            ahz = fmaf(hv[k], ld<true>(Whh, (64 + c) * D + k), ahz);
            ahn = fmaf(hv[k], ld<true>(Whh, (128 + c) * D + k), ahn);
        }
        float r = 1.f / (1.f + __expf(-(air + ahr)));
        float z = 1.f / (1.f + __expf(-(aiz + ahz)));
        float nx = ain + r * ahn;
        float nn = 1.f - 2.f / (1.f + __expf(2.f * nx));
        float hcur = h[(size_t)n * D + c];
        float hn = (1.f - z) * nn + z * hcur;
        if (hout) hout[(size_t)n * D + c] = hn;
        else ((float*)obuf)[(size_t)n * D + c] = hn;
    }
}

// fast kernel: grid = ceil(N/16) blocks; internal f32 fallback uses node-grid math,
// so for flags[0] we launch enough blocks for BOTH mappings (host uses max grid).
__global__ __launch_bounds__(256) void gru_fast_kernel(const int* flags,
                                                       const float* agg, const float* h,
                                                       const uint32_t* WT2,
                                                       const void* Wih, const void* Whh,
                                                       const void* bih, const void* bhh,
                                                       float* hout, bf16* obf, int N) {
    __shared__ float LA[16 * 66];
    __shared__ float LH[16 * 66];
    __shared__ float LB[384];
    if (flags[0]) gru_body_f32(agg, h, Wih, Whh, bih, bhh, hout, (void*)obf, N);
    else gru_fast_bf16(LA, LH, LB, agg, h, WT2, bih, bhh, hout, obf, N);
}

// round-6 gru (both dtypes, no WT2) — fallback if ws is too small for WT2
template <bool F32>
__device__ __forceinline__ void gru_old_body(const float* agg, const float* h,
                                             const void* Wih, const void* Whh,
                                             const void* bih, const void* bhh,
                                             float* hout, void* obuf, int N) {
    int lane = threadIdx.x & 63;
    int sub = threadIdx.x >> 6;
    int n = blockIdx.x * 64 + lane;
    if (n >= N) return;
    float ar[D], hv[D];
    const float4* a4 = (const float4*)(agg + (size_t)n * D);
    const float4* h4 = (const float4*)(h + (size_t)n * D);
#pragma unroll
    for (int i = 0; i < 16; ++i) {
        float4 v = a4[i];
        ar[4 * i] = v.x; ar[4 * i + 1] = v.y; ar[4 * i + 2] = v.z; ar[4 * i + 3] = v.w;
        float4 w = h4[i];
        hv[4 * i] = w.x; hv[4 * i + 1] = w.y; hv[4 * i + 2] = w.z; hv[4 * i + 3] = w.w;
    }
    int c0 = sub * 16;
#pragma unroll 1
    for (int cc = 0; cc < 16; ++cc) {
        int c = c0 + cc;
        float air = ld<F32>(bih, c), aiz = ld<F32>(bih, 64 + c), ain = ld<F32>(bih, 128 + c);
        float ahr = ld<F32>(bhh, c), ahz = ld<F32>(bhh, 64 + c), ahn = ld<F32>(bhh, 128 + c);
#pragma unroll
        for (int k = 0; k < D; ++k) {
            air = fmaf(ar[k], ld<F32>(Wih, c * D + k), air);
            aiz = fmaf(ar[k], ld<F32>(Wih, (64 + c) * D + k), aiz);
            ain = fmaf(ar[k], ld<F32>(Wih, (128 + c) * D + k), ain);
            ahr = fmaf(hv[k], ld<F32>(Whh, c * D + k), ahr);
            ahz = fmaf(hv[k], ld<F32>(Whh, (64 + c) * D + k), ahz);
            ahn = fmaf(hv[k], ld<F32>(Whh, (128 + c) * D + k), ahn);
        }
        float r = 1.f / (1.f + __expf(-(air + ahr)));
        float z = 1.f / (1.f + __expf(-(aiz + ahz)));
        float nx = ain + r * ahn;
        float nn = 1.f - 2.f / (1.f + __expf(2.f * nx));
        float hcur = h[(size_t)n * D + c];
        float hn = (1.f - z) * nn + z * hcur;
        if (hout) hout[(size_t)n * D + c] = hn;
        else if (F32) ((float*)obuf)[(size_t)n * D + c] = hn;
        else ((bf16*)obuf)[(size_t)n * D + c] = __float2bfloat16(hn);
    }
}
__global__ __launch_bounds__(256, 1) void gru_old_kernel(const int* flags, const float* agg,
                                                         const float* h,
                                                         const void* Wih, const void* Whh,
                                                         const void* bih, const void* bhh,
                                                         float* hout, void* obuf, int N) {
    if (flags[0]) gru_old_body<true>(agg, h, Wih, Whh, bih, bhh, hout, obuf, N);
    else          gru_old_body<false>(agg, h, Wih, Whh, bih, bhh, hout, obuf, N);
}

extern "C" void kernel_launch(void* const* d_in, const int* in_sizes, int n_in,
                              void* d_out, int out_size, void* d_ws, size_t ws_size,
                              hipStream_t stream) {
    const void* x   = d_in[0];
    const int*  ei  = (const int*)d_in[1];
    const void* Wnt = d_in[4];
    const void* bnt = d_in[5];
    const void* Wt  = d_in[6];
    const void* Wih = d_in[7];
    const void* Whh = d_in[8];
    const void* bih = d_in[9];
    const void* bhh = d_in[10];

    int N = in_sizes[0] / 6;
    int E = in_sizes[1] / 2;

    int* flags = (int*)d_ws;
    float* B0 = (float*)((char*)d_ws + 256);
    float* B1 = B0 + (size_t)N * D;
    float* B2 = B1 + (size_t)N * D;
    uint32_t* WT2 = (uint32_t*)(B2 + (size_t)N * D);  // 12288 dwords = 48 KB
    size_t need = 256 + 3 * (size_t)N * D * sizeof(float) + 12288 * sizeof(uint32_t);
    bool fast = (ws_size >= need);  // host-known, identical every call (graph-safe)

    detect_kernel<<<1, 256, 0, stream>>>(x, ei, flags);
    nt_kernel<<<(N * D + 255) / 256, 256, 0, stream>>>(flags, x, Wnt, bnt, B0, N);
    if (fast)
        wtrans_kernel<<<48, 256, 0, stream>>>((const uint32_t*)Wih, (const uint32_t*)Whh, WT2);

    float* h = B0;
    float* mbuf = B1;
    float* agg = B2;
    for (int layer = 0; layer < 3; ++layer) {
        m_kernel<<<(N + 3) / 4, 256, 0, stream>>>(flags, h, Wt, layer * D * D, mbuf, N);
        hipMemsetAsync(agg, 0, (size_t)N * D * sizeof(float), stream);
        scatter_kernel<<<(E + 3) / 4, 256, 0, stream>>>(flags, mbuf, ei, agg, E, N);
        bool last = (layer == 2);
        if (fast) {
            // grid must cover both mappings: bf16 fast = N/16 nodes/block, f32 old = N/64.
            int grid = (N + 15) / 16;
            gru_fast_kernel<<<grid, 256, 0, stream>>>(flags, agg, h, WT2, Wih, Whh, bih, bhh,
                                                      last ? nullptr : mbuf,
                                                      last ? (bf16*)d_out : nullptr, N);
        } else {
            gru_old_kernel<<<(N + 63) / 64, 256, 0, stream>>>(flags, agg, h, Wih, Whh, bih, bhh,
                                                              last ? nullptr : mbuf,
                                                              last ? d_out : nullptr, N);
        }
        float* t = h; h = mbuf; mbuf = t;
    }
}